// Round 5
// baseline (668.668 us; speedup 1.0000x reference)
//
#include <hip/hip_runtime.h>
#include <hip/hip_cooperative_groups.h>

namespace cg = cooperative_groups;

#define N_FUNC 10000
#define N_IN   2000
#define N_OUT  2000
#define CCH    8
#define K_FF   16
#define E_TOTAL 170000
#define E_FF    160000   // ff edges: dst[e] = e/16 (structural), src random func
#define E_W1    168000   // ff+if edges (dst < N_FUNC)
#define E_IF    8000
#define BATCH   64
#define N_LAYERS 4
#define EPS_LN  1e-5f

#define SRC_CAP 64   // max out-degree of a func node (fixed graph, mean 16.2, max ~45)
#define IF_CAP  16   // max if-in-degree of a func node (mean 0.8)

// bf16 storage helpers: fp32 math everywhere, RNE on store.
__device__ __forceinline__ float bf2f(unsigned short u) {
    unsigned int x = ((unsigned int)u) << 16;
    return __builtin_bit_cast(float, x);
}
__device__ __forceinline__ unsigned short f2bf(float f) {
    unsigned int x = __builtin_bit_cast(unsigned int, f);
    unsigned int r = x + 0x7FFFu + ((x >> 16) & 1u);
    return (unsigned short)(r >> 16);
}

// k1 body: gather -> group-LN -> GELU, h stays in registers
__device__ __forceinline__ void compute_h(
        const unsigned short* __restrict__ xe_old, const float* __restrict__ xT,
        const float* __restrict__ w1, const float* __restrict__ b1,
        const float* __restrict__ gamma, const float* __restrict__ beta,
        const float* __restrict__ b3, const int* __restrict__ if_cnt,
        const int* __restrict__ if_bkt, int f, int lane, int layer, bool first,
        float* __restrict__ hreg) {
    float acc[CCH];
    #pragma unroll
    for (int c = 0; c < CCH; c++) acc[c] = b1[f * CCH + c];

    if (!first) {
        // ff in-edges: rows 16f..16f+15 (structural); all 16 loads in flight
        float xv[K_FF];
        #pragma unroll
        for (int k = 0; k < K_FF; k++) xv[k] = bf2f(xe_old[(f * K_FF + k) * BATCH + lane]);
        #pragma unroll
        for (int k = 0; k < K_FF; k++) {
            const float* wr = w1 + (size_t)(f * K_FF + k) * CCH;
            #pragma unroll
            for (int c = 0; c < CCH; c++) acc[c] += xv[k] * wr[c];
        }
    }
    // if in-edges: virtual xe row = xT[i] + layer*b3[e] (never materialized)
    int icnt = if_cnt[f];
    float lf = (float)layer;
    for (int j = 0; j < icnt; j++) {
        int e = if_bkt[f * IF_CAP + j];
        int ii = (e - E_FF) >> 2;
        float xv = xT[ii * BATCH + lane] + lf * b3[e];
        const float* wr = w1 + (size_t)e * CCH;
        #pragma unroll
        for (int c = 0; c < CCH; c++) acc[c] += xv * wr[c];
    }
    // group-LN over 8 channels (lane-local) + exact GELU
    float mu = 0.f;
    #pragma unroll
    for (int c = 0; c < CCH; c++) mu += acc[c];
    mu *= 0.125f;
    float var = 0.f;
    #pragma unroll
    for (int c = 0; c < CCH; c++) { float d = acc[c] - mu; var += d * d; }
    var *= 0.125f;
    float rs = rsqrtf(var + EPS_LN);
    #pragma unroll
    for (int c = 0; c < CCH; c++) {
        float g = (acc[c] - mu) * rs * gamma[f * CCH + c] + beta[f * CCH + c];
        hreg[c] = 0.5f * g * (1.0f + erff(g * 0.70710678118654752f));
    }
}

// scatter a chunk of CH out-edges: all residual loads in flight before FMAs
template <int CH>
__device__ __forceinline__ void scat_chunk(
        const int* __restrict__ bkt, int j, bool first,
        const unsigned short* __restrict__ xe_old, unsigned short* __restrict__ xe_new,
        const float* __restrict__ w3, const float* __restrict__ b3,
        const float* __restrict__ hreg, int lane) {
    int e[CH];
    float r[CH];
    #pragma unroll
    for (int q = 0; q < CH; q++) e[q] = bkt[j + q];
    #pragma unroll
    for (int q = 0; q < CH; q++)
        r[q] = first ? 0.f : bf2f(xe_old[(size_t)e[q] * BATCH + lane]);
    #pragma unroll
    for (int q = 0; q < CH; q++) {
        int p = (e[q] < E_FF) ? e[q] : (e[q] - E_IF);
        const float* wr = w3 + (size_t)p * CCH;
        float a = b3[e[q]] + r[q];
        #pragma unroll
        for (int c = 0; c < CCH; c++) a += hreg[c] * wr[c];
        xe_new[(size_t)e[q] * BATCH + lane] = f2bf(a);
    }
}

// ---------------- the whole network in one cooperative kernel ----------------

__global__ __launch_bounds__(256, 4) void gsnn_all(
        const float* __restrict__ x, const float* __restrict__ w1,
        const float* __restrict__ b1, const float* __restrict__ w3,
        const float* __restrict__ b3, const float* __restrict__ gamma,
        const float* __restrict__ beta, const int* __restrict__ esrc,
        const int* __restrict__ edst, float* __restrict__ out,
        unsigned short* __restrict__ xeA, unsigned short* __restrict__ xeB,
        float* __restrict__ xT, int* __restrict__ src_cnt, int* __restrict__ if_cnt,
        int* __restrict__ src_bkt, int* __restrict__ if_bkt) {
    cg::grid_group grid = cg::this_grid();
    const int tid = blockIdx.x * blockDim.x + threadIdx.x;
    const int nthr = gridDim.x * blockDim.x;
    const int lane = threadIdx.x & 63;
    const int wave0 = tid >> 6;
    const int nwaves = nthr >> 6;

    // P0: zero bucket counts
    for (int i = tid; i < N_FUNC; i += nthr) { src_cnt[i] = 0; if_cnt[i] = 0; }
    grid.sync();

    // P1: build buckets + x transpose
    for (int i = tid; i < E_FF + N_OUT; i += nthr) {
        int e = (i < E_FF) ? i : (E_W1 + (i - E_FF));
        int s = esrc[e];
        int pos = atomicAdd(&src_cnt[s], 1);
        src_bkt[s * SRC_CAP + pos] = e;
    }
    for (int i = tid; i < E_IF; i += nthr) {
        int e = E_FF + i;
        int d = edst[e];
        int pos = atomicAdd(&if_cnt[d], 1);
        if_bkt[d * IF_CAP + pos] = e;
    }
    for (int i = tid; i < N_IN * BATCH; i += nthr) {
        int col = i >> 6, b = i & 63;
        xT[col * BATCH + b] = x[b * N_IN + col];
    }
    grid.sync();

    // layers 0..2: wave-per-node, double-buffered xe.
    // Persistent blocks: the rows this wave writes now are the rows it reads
    // as residuals next layer -> XCD-local L2 hits.
    const unsigned short* oldp = xeA;   // layer 0 never reads it (first=true)
    unsigned short* newp = xeB;
    for (int l = 0; l < 3; l++) {
        const bool first = (l == 0);
        for (int f0 = wave0; f0 < N_FUNC; f0 += nwaves) {
            int f = __builtin_amdgcn_readfirstlane(f0);
            float hreg[CCH];
            compute_h(oldp, xT, w1, b1, gamma, beta, b3, if_cnt, if_bkt,
                      f, lane, l, first, hreg);
            const int* bkt = src_bkt + f * SRC_CAP;
            int ocnt = src_cnt[f];
            int j = 0;
            for (; j + 8 <= ocnt; j += 8)
                scat_chunk<8>(bkt, j, first, oldp, newp, w3, b3, hreg, lane);
            for (; j + 4 <= ocnt; j += 4)
                scat_chunk<4>(bkt, j, first, oldp, newp, w3, b3, hreg, lane);
            for (; j + 2 <= ocnt; j += 2)
                scat_chunk<2>(bkt, j, first, oldp, newp, w3, b3, hreg, lane);
            for (; j < ocnt; j++)
                scat_chunk<1>(bkt, j, first, oldp, newp, w3, b3, hreg, lane);
        }
        grid.sync();
        const unsigned short* t = oldp; oldp = newp; newp = (unsigned short*)t;
    }
    // after 3 swaps: oldp == xeB (layer-2 output)

    // layer 3: only the 2000 fo edges feed the output
    for (int j0 = wave0; j0 < N_OUT; j0 += nwaves) {
        int j = __builtin_amdgcn_readfirstlane(j0);
        int e = E_W1 + j;
        int s = __builtin_amdgcn_readfirstlane(esrc[e]);
        float hreg[CCH];
        compute_h(oldp, xT, w1, b1, gamma, beta, b3, if_cnt, if_bkt,
                  s, lane, N_LAYERS - 1, false, hreg);
        int p = e - E_IF;
        const float* wr = w3 + (size_t)p * CCH;
        float acc = bf2f(oldp[(size_t)e * BATCH + lane]) + b3[e];
        #pragma unroll
        for (int c = 0; c < CCH; c++) acc += hreg[c] * wr[c];
        out[lane * N_OUT + j] = acc * (1.0f / N_LAYERS);
    }
}

// ---------------- launch ----------------

extern "C" void kernel_launch(void* const* d_in, const int* in_sizes, int n_in,
                              void* d_out, int out_size, void* d_ws, size_t ws_size,
                              hipStream_t stream) {
    const float* x      = (const float*)d_in[0];
    const float* w1_val = (const float*)d_in[1];
    const float* b1     = (const float*)d_in[2];
    const float* w3_val = (const float*)d_in[3];
    const float* b3     = (const float*)d_in[4];
    const float* gamma  = (const float*)d_in[5];
    const float* beta   = (const float*)d_in[6];
    const int* edge_src = (const int*)d_in[7];
    const int* edge_dst = (const int*)d_in[8];
    float* out = (float*)d_out;

    char* base = (char*)d_ws;
    size_t off = 0;
    auto alloc = [&](size_t bytes) -> void* {
        void* p = base + off;
        off += (bytes + 255) & ~(size_t)255;
        return p;
    };
    unsigned short* xeA = (unsigned short*)alloc((size_t)E_TOTAL * BATCH * 2);
    unsigned short* xeB = (unsigned short*)alloc((size_t)E_TOTAL * BATCH * 2);
    float* xT     = (float*)alloc((size_t)N_IN * BATCH * 4);
    int* src_cnt  = (int*)alloc(N_FUNC * 4);
    int* if_cnt   = (int*)alloc(N_FUNC * 4);
    int* src_bkt  = (int*)alloc((size_t)N_FUNC * SRC_CAP * 4);
    int* if_bkt   = (int*)alloc((size_t)N_FUNC * IF_CAP * 4);
    (void)ws_size; (void)in_sizes; (void)n_in; (void)out_size;

    // co-residency-bounded grid (host-side query, graph-capture legal)
    int nb = 0;
    hipOccupancyMaxActiveBlocksPerMultiprocessor(&nb, gsnn_all, 256, 0);
    if (nb < 1) nb = 1;
    int grid = nb * 256;            // 256 CUs
    if (grid > 2048) grid = 2048;

    void* args[] = {
        (void*)&x, (void*)&w1_val, (void*)&b1, (void*)&w3_val, (void*)&b3,
        (void*)&gamma, (void*)&beta, (void*)&edge_src, (void*)&edge_dst,
        (void*)&out, (void*)&xeA, (void*)&xeB, (void*)&xT,
        (void*)&src_cnt, (void*)&if_cnt, (void*)&src_bkt, (void*)&if_bkt
    };
    hipLaunchCooperativeKernel(gsnn_all, dim3(grid), dim3(256), args, 0, stream);
}

// Round 6
// 190.182 us; speedup vs baseline: 3.5159x; 3.5159x over previous
//
#include <hip/hip_runtime.h>

#define N_FUNC 10000
#define N_IN   2000
#define N_OUT  2000
#define CCH    8
#define K_FF   16
#define E_TOTAL 170000
#define E_FF    160000   // ff edges: dst[e] = e/16 (structural), src random func
#define E_W1    168000   // ff+if edges (dst < N_FUNC)
#define E_IF    8000
#define BATCH   64
#define N_LAYERS 4
#define EPS_LN  1e-5f

#define SRC_CAP 64   // max out-degree of a func node (fixed graph, mean 16.2, max ~45)
#define IF_CAP  16   // max if-in-degree of a func node (mean 0.8)

// bf16 storage helpers: fp32 math everywhere, RNE on store.
__device__ __forceinline__ float bf2f(unsigned short u) {
    unsigned int x = ((unsigned int)u) << 16;
    return __builtin_bit_cast(float, x);
}
__device__ __forceinline__ unsigned short f2bf(float f) {
    unsigned int x = __builtin_bit_cast(unsigned int, f);
    unsigned int r = x + 0x7FFFu + ((x >> 16) & 1u);
    return (unsigned short)(r >> 16);
}

// ---------------- prep 1: zero counts + x transpose (independent work, fused) --

__global__ void prep_zero_xt(int* __restrict__ src_cnt, int* __restrict__ if_cnt,
                             const float* __restrict__ x, float* __restrict__ xT) {
    int i = blockIdx.x * blockDim.x + threadIdx.x;
    if (i < N_FUNC) { src_cnt[i] = 0; if_cnt[i] = 0; }
    if (i < N_IN * BATCH) {
        int col = i >> 6, lane = i & 63;
        xT[col * BATCH + lane] = x[lane * N_IN + col];
    }
}

// ---------------- prep 2: bucket build ----------------

__global__ void fill_buckets(const int* __restrict__ src, const int* __restrict__ dst,
                             int* __restrict__ src_cnt, int* __restrict__ src_bkt,
                             int* __restrict__ if_cnt, int* __restrict__ if_bkt) {
    int i = blockIdx.x * blockDim.x + threadIdx.x;
    if (i < E_FF + N_OUT) {            // w3 edges (src is a func node)
        int e = (i < E_FF) ? i : (E_W1 + (i - E_FF));
        int s = src[e];
        int pos = atomicAdd(&src_cnt[s], 1);
        src_bkt[s * SRC_CAP + pos] = e;
    }
    if (i < E_IF) {                    // if edges, bucketed by dst
        int e = E_FF + i;
        int d = dst[e];
        int pos = atomicAdd(&if_cnt[d], 1);
        if_bkt[d * IF_CAP + pos] = e;
    }
}

// ---------------- k1 body: gather -> group-LN -> GELU (h stays in registers) ---

__device__ __forceinline__ void compute_h(
        const unsigned short* __restrict__ xe_old, const float* __restrict__ xT,
        const float* __restrict__ w1, const float* __restrict__ b1,
        const float* __restrict__ gamma, const float* __restrict__ beta,
        const float* __restrict__ b3, const int* __restrict__ if_cnt,
        const int* __restrict__ if_bkt, int f, int lane, int layer, bool first,
        float* __restrict__ hreg) {
    float acc[CCH];
    #pragma unroll
    for (int c = 0; c < CCH; c++) acc[c] = b1[f * CCH + c];

    if (!first) {
        // ff in-edges: rows 16f..16f+15 (structural); all 16 loads in flight
        float xv[K_FF];
        #pragma unroll
        for (int k = 0; k < K_FF; k++) xv[k] = bf2f(xe_old[(f * K_FF + k) * BATCH + lane]);
        #pragma unroll
        for (int k = 0; k < K_FF; k++) {
            const float* wr = w1 + (size_t)(f * K_FF + k) * CCH;
            #pragma unroll
            for (int c = 0; c < CCH; c++) acc[c] += xv[k] * wr[c];
        }
    }
    // if in-edges: virtual xe row = xT[i] + layer*b3[e] (never materialized)
    int icnt = if_cnt[f];
    float lf = (float)layer;
    for (int j = 0; j < icnt; j++) {
        int e = if_bkt[f * IF_CAP + j];
        int ii = (e - E_FF) >> 2;
        float xv = xT[ii * BATCH + lane] + lf * b3[e];
        const float* wr = w1 + (size_t)e * CCH;
        #pragma unroll
        for (int c = 0; c < CCH; c++) acc[c] += xv * wr[c];
    }
    // group-LN over 8 channels (lane-local) + exact GELU
    float mu = 0.f;
    #pragma unroll
    for (int c = 0; c < CCH; c++) mu += acc[c];
    mu *= 0.125f;
    float var = 0.f;
    #pragma unroll
    for (int c = 0; c < CCH; c++) { float d = acc[c] - mu; var += d * d; }
    var *= 0.125f;
    float rs = rsqrtf(var + EPS_LN);
    #pragma unroll
    for (int c = 0; c < CCH; c++) {
        float g = (acc[c] - mu) * rs * gamma[f * CCH + c] + beta[f * CCH + c];
        hreg[c] = 0.5f * g * (1.0f + erff(g * 0.70710678118654752f));
    }
}

// scatter a chunk of CH out-edges: ALL residual loads issued before any FMA.
// edge ids are wave-uniform (bkt base is readfirstlane'd) -> SGPR-resident.
template <int CH>
__device__ __forceinline__ void scat_chunk(
        const int* __restrict__ bkt, int j, bool first,
        const unsigned short* __restrict__ xe_old, unsigned short* __restrict__ xe_new,
        const float* __restrict__ w3, const float* __restrict__ b3,
        const float* __restrict__ hreg, int lane) {
    int e[CH];
    float r[CH];
    #pragma unroll
    for (int q = 0; q < CH; q++) e[q] = bkt[j + q];
    #pragma unroll
    for (int q = 0; q < CH; q++)
        r[q] = first ? 0.f : bf2f(xe_old[(size_t)e[q] * BATCH + lane]);
    #pragma unroll
    for (int q = 0; q < CH; q++) {
        int p = (e[q] < E_FF) ? e[q] : (e[q] - E_IF);
        const float* wr = w3 + (size_t)p * CCH;
        float a = b3[e[q]] + r[q];
        #pragma unroll
        for (int c = 0; c < CCH; c++) a += hreg[c] * wr[c];
        xe_new[(size_t)e[q] * BATCH + lane] = f2bf(a);
    }
}

// ---------------- fused layer: k1 (regs) + scatter to out-edges ----------------
// one wave per func node; double-buffered xe (read old, write new).

template <bool FIRST>
__global__ __launch_bounds__(256, 4) void layer_fused(
        const unsigned short* __restrict__ xe_old, unsigned short* __restrict__ xe_new,
        const float* __restrict__ xT, const float* __restrict__ w1,
        const float* __restrict__ b1, const float* __restrict__ gamma,
        const float* __restrict__ beta, const float* __restrict__ w3,
        const float* __restrict__ b3, const int* __restrict__ if_cnt,
        const int* __restrict__ if_bkt, const int* __restrict__ src_cnt,
        const int* __restrict__ src_bkt, int layer) {
    int wid = (blockIdx.x * blockDim.x + threadIdx.x) >> 6;
    int lane = threadIdx.x & 63;
    int f = __builtin_amdgcn_readfirstlane(wid);
    if (f >= N_FUNC) return;

    float hreg[CCH];
    compute_h(xe_old, xT, w1, b1, gamma, beta, b3, if_cnt, if_bkt,
              f, lane, layer, FIRST, hreg);

    // scatter: out-edges of f (ff + fo), residual from old buffer.
    // 16-wide rounds: most nodes (deg<=16, ~54%) finish in ONE latency round,
    // 99.9% within two. (mean out-degree 16.2, max ~45 < SRC_CAP.)
    const int* bkt = src_bkt + f * SRC_CAP;
    int ocnt = src_cnt[f];
    int j = 0;
    for (; j + 16 <= ocnt; j += 16)
        scat_chunk<16>(bkt, j, FIRST, xe_old, xe_new, w3, b3, hreg, lane);
    for (; j + 8 <= ocnt; j += 8)
        scat_chunk<8>(bkt, j, FIRST, xe_old, xe_new, w3, b3, hreg, lane);
    for (; j + 4 <= ocnt; j += 4)
        scat_chunk<4>(bkt, j, FIRST, xe_old, xe_new, w3, b3, hreg, lane);
    for (; j + 2 <= ocnt; j += 2)
        scat_chunk<2>(bkt, j, FIRST, xe_old, xe_new, w3, b3, hreg, lane);
    for (; j < ocnt; j++)
        scat_chunk<1>(bkt, j, FIRST, xe_old, xe_new, w3, b3, hreg, lane);
}

// ---------------- last layer: only 2000 fo edges matter -> fused with output ----
// one wave per fo edge; recompute h[src] (<=2000 nodes vs 10000).

__global__ __launch_bounds__(256, 4) void layer_last(
        const unsigned short* __restrict__ xe_old, const float* __restrict__ xT,
        const float* __restrict__ w1, const float* __restrict__ b1,
        const float* __restrict__ gamma, const float* __restrict__ beta,
        const float* __restrict__ w3, const float* __restrict__ b3,
        const int* __restrict__ if_cnt, const int* __restrict__ if_bkt,
        const int* __restrict__ edge_src, float* __restrict__ out) {
    int wid = (blockIdx.x * blockDim.x + threadIdx.x) >> 6;   // fo index j
    int lane = threadIdx.x & 63;
    int j = __builtin_amdgcn_readfirstlane(wid);
    if (j >= N_OUT) return;
    int e = E_W1 + j;
    int s = __builtin_amdgcn_readfirstlane(edge_src[e]);

    float hreg[CCH];
    compute_h(xe_old, xT, w1, b1, gamma, beta, b3, if_cnt, if_bkt,
              s, lane, N_LAYERS - 1, false, hreg);

    int p = e - E_IF;
    const float* wr = w3 + (size_t)p * CCH;
    float acc = bf2f(xe_old[(size_t)e * BATCH + lane]) + b3[e];
    #pragma unroll
    for (int c = 0; c < CCH; c++) acc += hreg[c] * wr[c];
    out[lane * N_OUT + j] = acc * (1.0f / N_LAYERS);
}

// ---------------- launch ----------------

extern "C" void kernel_launch(void* const* d_in, const int* in_sizes, int n_in,
                              void* d_out, int out_size, void* d_ws, size_t ws_size,
                              hipStream_t stream) {
    const float* x      = (const float*)d_in[0];
    const float* w1_val = (const float*)d_in[1];
    const float* b1     = (const float*)d_in[2];
    const float* w3_val = (const float*)d_in[3];
    const float* b3     = (const float*)d_in[4];
    const float* gamma  = (const float*)d_in[5];
    const float* beta   = (const float*)d_in[6];
    const int* edge_src = (const int*)d_in[7];
    const int* edge_dst = (const int*)d_in[8];
    float* out = (float*)d_out;

    char* base = (char*)d_ws;
    size_t off = 0;
    auto alloc = [&](size_t bytes) -> void* {
        void* p = base + off;
        off += (bytes + 255) & ~(size_t)255;
        return p;
    };
    unsigned short* xeA = (unsigned short*)alloc((size_t)E_TOTAL * BATCH * 2);  // bf16
    unsigned short* xeB = (unsigned short*)alloc((size_t)E_TOTAL * BATCH * 2);  // bf16
    float* xT     = (float*)alloc((size_t)N_IN * BATCH * 4);
    int* src_cnt  = (int*)alloc(N_FUNC * 4);
    int* if_cnt   = (int*)alloc(N_FUNC * 4);
    int* src_bkt  = (int*)alloc((size_t)N_FUNC * SRC_CAP * 4);
    int* if_bkt   = (int*)alloc((size_t)N_FUNC * IF_CAP * 4);
    (void)ws_size; (void)in_sizes; (void)n_in; (void)out_size;

    prep_zero_xt<<<(N_IN * BATCH + 255) / 256, 256, 0, stream>>>(src_cnt, if_cnt, x, xT);
    fill_buckets<<<(E_FF + N_OUT + 255) / 256, 256, 0, stream>>>(
        edge_src, edge_dst, src_cnt, src_bkt, if_cnt, if_bkt);

    // layer 0: old=xeA (never read; FIRST skips all old reads), new=xeB
    layer_fused<true><<<(N_FUNC * BATCH) / 256, 256, 0, stream>>>(
        xeA, xeB, xT, w1_val, b1, gamma, beta, w3_val, b3,
        if_cnt, if_bkt, src_cnt, src_bkt, 0);
    // layer 1: B -> A
    layer_fused<false><<<(N_FUNC * BATCH) / 256, 256, 0, stream>>>(
        xeB, xeA, xT, w1_val, b1, gamma, beta, w3_val, b3,
        if_cnt, if_bkt, src_cnt, src_bkt, 1);
    // layer 2: A -> B
    layer_fused<false><<<(N_FUNC * BATCH) / 256, 256, 0, stream>>>(
        xeA, xeB, xT, w1_val, b1, gamma, beta, w3_val, b3,
        if_cnt, if_bkt, src_cnt, src_bkt, 2);
    // layer 3: read B, write only the 2000 outputs
    layer_last<<<(N_OUT * BATCH) / 256, 256, 0, stream>>>(
        xeB, xT, w1_val, b1, gamma, beta, w3_val, b3,
        if_cnt, if_bkt, edge_src, out);
}

// Round 7
// 186.068 us; speedup vs baseline: 3.5937x; 1.0221x over previous
//
#include <hip/hip_runtime.h>

#define N_FUNC 10000
#define N_IN   2000
#define N_OUT  2000
#define CCH    8
#define K_FF   16
#define E_TOTAL 170000
#define E_FF    160000   // ff edges: dst[e] = e/16 (structural), src random func
#define E_W1    168000   // ff+if edges (dst < N_FUNC)
#define E_IF    8000
#define BATCH   64
#define N_LAYERS 4
#define EPS_LN  1e-5f

#define SRC_CAP 64   // max out-degree of a func node (fixed graph, mean 16.2, max ~45)
#define IF_CAP  16   // max if-in-degree of a func node (mean 0.8)

// bf16 storage helpers: fp32 math everywhere, RNE on store.
__device__ __forceinline__ float bf2f(unsigned short u) {
    unsigned int x = ((unsigned int)u) << 16;
    return __builtin_bit_cast(float, x);
}
__device__ __forceinline__ unsigned short f2bf(float f) {
    unsigned int x = __builtin_bit_cast(unsigned int, f);
    unsigned int r = x + 0x7FFFu + ((x >> 16) & 1u);
    return (unsigned short)(r >> 16);
}

// fast GELU: x * sigmoid(1.5957691*(x + 0.044715 x^3)), sigmoid via native
// exp2 + rcp. |err vs exact erf-GELU| <= ~3e-3 abs — far under bf16 threshold.
// ~8 VALU vs ~30 for erff.
__device__ __forceinline__ float fast_gelu(float x) {
    float x2 = x * x;
    float u  = x * __builtin_fmaf(0.044715f, x2, 1.0f);   // x + 0.044715 x^3
    float z2 = -2.3022080f * u;                            // -1.5957691*log2(e)*u... (exp2 arg)
#if __has_builtin(__builtin_amdgcn_exp2f)
    float e = __builtin_amdgcn_exp2f(z2);
#else
    float e = exp2f(z2);
#endif
    float d = 1.0f + e;
#if __has_builtin(__builtin_amdgcn_rcpf)
    float r = __builtin_amdgcn_rcpf(d);
#else
    float r = 1.0f / d;
#endif
    return x * r;
}

// ---------------- prep 1: zero counts + x transpose (independent work, fused) --

__global__ void prep_zero_xt(int* __restrict__ src_cnt, int* __restrict__ if_cnt,
                             const float* __restrict__ x, float* __restrict__ xT) {
    int i = blockIdx.x * blockDim.x + threadIdx.x;
    if (i < N_FUNC) { src_cnt[i] = 0; if_cnt[i] = 0; }
    if (i < N_IN * BATCH) {
        int col = i >> 6, lane = i & 63;
        xT[col * BATCH + lane] = x[lane * N_IN + col];
    }
}

// ---------------- prep 2: bucket build ----------------

__global__ void fill_buckets(const int* __restrict__ src, const int* __restrict__ dst,
                             int* __restrict__ src_cnt, int* __restrict__ src_bkt,
                             int* __restrict__ if_cnt, int* __restrict__ if_bkt) {
    int i = blockIdx.x * blockDim.x + threadIdx.x;
    if (i < E_FF + N_OUT) {            // w3 edges (src is a func node)
        int e = (i < E_FF) ? i : (E_W1 + (i - E_FF));
        int s = src[e];
        int pos = atomicAdd(&src_cnt[s], 1);
        src_bkt[s * SRC_CAP + pos] = e;
    }
    if (i < E_IF) {                    // if edges, bucketed by dst
        int e = E_FF + i;
        int d = dst[e];
        int pos = atomicAdd(&if_cnt[d], 1);
        if_bkt[d * IF_CAP + pos] = e;
    }
}

// ---------------- k1 body: gather -> group-LN -> GELU (h stays in registers) ---

__device__ __forceinline__ void compute_h(
        const unsigned short* __restrict__ xe_old, const float* __restrict__ xT,
        const float* __restrict__ w1, const float* __restrict__ b1,
        const float* __restrict__ gamma, const float* __restrict__ beta,
        const float* __restrict__ b3, const int* __restrict__ if_cnt,
        const int* __restrict__ if_bkt, int f, int lane, int layer, bool first,
        float* __restrict__ hreg) {
    float acc[CCH];
    #pragma unroll
    for (int c = 0; c < CCH; c++) acc[c] = b1[f * CCH + c];

    if (!first) {
        // ff in-edges: rows 16f..16f+15 (structural); all 16 loads in flight
        float xv[K_FF];
        #pragma unroll
        for (int k = 0; k < K_FF; k++) xv[k] = bf2f(xe_old[(f * K_FF + k) * BATCH + lane]);
        #pragma unroll
        for (int k = 0; k < K_FF; k++) {
            const float* wr = w1 + (size_t)(f * K_FF + k) * CCH;
            #pragma unroll
            for (int c = 0; c < CCH; c++) acc[c] += xv[k] * wr[c];
        }
    }
    // if in-edges: virtual xe row = xT[i] + layer*b3[e] (never materialized)
    int icnt = if_cnt[f];
    float lf = (float)layer;
    for (int j = 0; j < icnt; j++) {
        int e = if_bkt[f * IF_CAP + j];
        int ii = (e - E_FF) >> 2;
        float xv = xT[ii * BATCH + lane] + lf * b3[e];
        const float* wr = w1 + (size_t)e * CCH;
        #pragma unroll
        for (int c = 0; c < CCH; c++) acc[c] += xv * wr[c];
    }
    // group-LN over 8 channels (lane-local) + fast GELU
    float mu = 0.f;
    #pragma unroll
    for (int c = 0; c < CCH; c++) mu += acc[c];
    mu *= 0.125f;
    float var = 0.f;
    #pragma unroll
    for (int c = 0; c < CCH; c++) { float d = acc[c] - mu; var += d * d; }
    var *= 0.125f;
    float rs = rsqrtf(var + EPS_LN);
    #pragma unroll
    for (int c = 0; c < CCH; c++) {
        float g = (acc[c] - mu) * rs * gamma[f * CCH + c] + beta[f * CCH + c];
        hreg[c] = fast_gelu(g);
    }
}

// scatter a chunk of CH out-edges: ALL residual loads issued before any FMA.
// edge ids are wave-uniform (bkt base is readfirstlane'd) -> SGPR-resident.
template <int CH>
__device__ __forceinline__ void scat_chunk(
        const int* __restrict__ bkt, int j, bool first,
        const unsigned short* __restrict__ xe_old, unsigned short* __restrict__ xe_new,
        const float* __restrict__ w3, const float* __restrict__ b3,
        const float* __restrict__ hreg, int lane) {
    int e[CH];
    float r[CH];
    #pragma unroll
    for (int q = 0; q < CH; q++) e[q] = bkt[j + q];
    #pragma unroll
    for (int q = 0; q < CH; q++)
        r[q] = first ? 0.f : bf2f(xe_old[(size_t)e[q] * BATCH + lane]);
    #pragma unroll
    for (int q = 0; q < CH; q++) {
        int p = (e[q] < E_FF) ? e[q] : (e[q] - E_IF);
        const float* wr = w3 + (size_t)p * CCH;
        float a = b3[e[q]] + r[q];
        #pragma unroll
        for (int c = 0; c < CCH; c++) a += hreg[c] * wr[c];
        xe_new[(size_t)e[q] * BATCH + lane] = f2bf(a);
    }
}

// ---------------- fused layer: k1 (regs) + scatter to out-edges ----------------
// one wave per func node; double-buffered xe (read old, write new).

template <bool FIRST>
__global__ __launch_bounds__(256, 4) void layer_fused(
        const unsigned short* __restrict__ xe_old, unsigned short* __restrict__ xe_new,
        const float* __restrict__ xT, const float* __restrict__ w1,
        const float* __restrict__ b1, const float* __restrict__ gamma,
        const float* __restrict__ beta, const float* __restrict__ w3,
        const float* __restrict__ b3, const int* __restrict__ if_cnt,
        const int* __restrict__ if_bkt, const int* __restrict__ src_cnt,
        const int* __restrict__ src_bkt, int layer) {
    int wid = (blockIdx.x * blockDim.x + threadIdx.x) >> 6;
    int lane = threadIdx.x & 63;
    int f = __builtin_amdgcn_readfirstlane(wid);
    if (f >= N_FUNC) return;

    float hreg[CCH];
    compute_h(xe_old, xT, w1, b1, gamma, beta, b3, if_cnt, if_bkt,
              f, lane, layer, FIRST, hreg);

    // scatter: out-edges of f (ff + fo), residual from old buffer.
    const int* bkt = src_bkt + f * SRC_CAP;
    int ocnt = src_cnt[f];
    int j = 0;
    for (; j + 16 <= ocnt; j += 16)
        scat_chunk<16>(bkt, j, FIRST, xe_old, xe_new, w3, b3, hreg, lane);
    for (; j + 8 <= ocnt; j += 8)
        scat_chunk<8>(bkt, j, FIRST, xe_old, xe_new, w3, b3, hreg, lane);
    for (; j + 4 <= ocnt; j += 4)
        scat_chunk<4>(bkt, j, FIRST, xe_old, xe_new, w3, b3, hreg, lane);
    for (; j + 2 <= ocnt; j += 2)
        scat_chunk<2>(bkt, j, FIRST, xe_old, xe_new, w3, b3, hreg, lane);
    for (; j < ocnt; j++)
        scat_chunk<1>(bkt, j, FIRST, xe_old, xe_new, w3, b3, hreg, lane);
}

// ---------------- last layer: only 2000 fo edges matter -> fused with output ----

__global__ __launch_bounds__(256, 4) void layer_last(
        const unsigned short* __restrict__ xe_old, const float* __restrict__ xT,
        const float* __restrict__ w1, const float* __restrict__ b1,
        const float* __restrict__ gamma, const float* __restrict__ beta,
        const float* __restrict__ w3, const float* __restrict__ b3,
        const int* __restrict__ if_cnt, const int* __restrict__ if_bkt,
        const int* __restrict__ edge_src, float* __restrict__ out) {
    int wid = (blockIdx.x * blockDim.x + threadIdx.x) >> 6;   // fo index j
    int lane = threadIdx.x & 63;
    int j = __builtin_amdgcn_readfirstlane(wid);
    if (j >= N_OUT) return;
    int e = E_W1 + j;
    int s = __builtin_amdgcn_readfirstlane(edge_src[e]);

    float hreg[CCH];
    compute_h(xe_old, xT, w1, b1, gamma, beta, b3, if_cnt, if_bkt,
              s, lane, N_LAYERS - 1, false, hreg);

    int p = e - E_IF;
    const float* wr = w3 + (size_t)p * CCH;
    float acc = bf2f(xe_old[(size_t)e * BATCH + lane]) + b3[e];
    #pragma unroll
    for (int c = 0; c < CCH; c++) acc += hreg[c] * wr[c];
    out[lane * N_OUT + j] = acc * (1.0f / N_LAYERS);
}

// ---------------- launch ----------------

extern "C" void kernel_launch(void* const* d_in, const int* in_sizes, int n_in,
                              void* d_out, int out_size, void* d_ws, size_t ws_size,
                              hipStream_t stream) {
    const float* x      = (const float*)d_in[0];
    const float* w1_val = (const float*)d_in[1];
    const float* b1     = (const float*)d_in[2];
    const float* w3_val = (const float*)d_in[3];
    const float* b3     = (const float*)d_in[4];
    const float* gamma  = (const float*)d_in[5];
    const float* beta   = (const float*)d_in[6];
    const int* edge_src = (const int*)d_in[7];
    const int* edge_dst = (const int*)d_in[8];
    float* out = (float*)d_out;

    char* base = (char*)d_ws;
    size_t off = 0;
    auto alloc = [&](size_t bytes) -> void* {
        void* p = base + off;
        off += (bytes + 255) & ~(size_t)255;
        return p;
    };
    unsigned short* xeA = (unsigned short*)alloc((size_t)E_TOTAL * BATCH * 2);  // bf16
    unsigned short* xeB = (unsigned short*)alloc((size_t)E_TOTAL * BATCH * 2);  // bf16
    float* xT     = (float*)alloc((size_t)N_IN * BATCH * 4);
    int* src_cnt  = (int*)alloc(N_FUNC * 4);
    int* if_cnt   = (int*)alloc(N_FUNC * 4);
    int* src_bkt  = (int*)alloc((size_t)N_FUNC * SRC_CAP * 4);
    int* if_bkt   = (int*)alloc((size_t)N_FUNC * IF_CAP * 4);
    (void)ws_size; (void)in_sizes; (void)n_in; (void)out_size;

    prep_zero_xt<<<(N_IN * BATCH + 255) / 256, 256, 0, stream>>>(src_cnt, if_cnt, x, xT);
    fill_buckets<<<(E_FF + N_OUT + 255) / 256, 256, 0, stream>>>(
        edge_src, edge_dst, src_cnt, src_bkt, if_cnt, if_bkt);

    // layer 0: old=xeA (never read; FIRST skips all old reads), new=xeB
    layer_fused<true><<<(N_FUNC * BATCH) / 256, 256, 0, stream>>>(
        xeA, xeB, xT, w1_val, b1, gamma, beta, w3_val, b3,
        if_cnt, if_bkt, src_cnt, src_bkt, 0);
    // layer 1: B -> A
    layer_fused<false><<<(N_FUNC * BATCH) / 256, 256, 0, stream>>>(
        xeB, xeA, xT, w1_val, b1, gamma, beta, w3_val, b3,
        if_cnt, if_bkt, src_cnt, src_bkt, 1);
    // layer 2: A -> B
    layer_fused<false><<<(N_FUNC * BATCH) / 256, 256, 0, stream>>>(
        xeA, xeB, xT, w1_val, b1, gamma, beta, w3_val, b3,
        if_cnt, if_bkt, src_cnt, src_bkt, 2);
    // layer 3: read B, write only the 2000 outputs
    layer_last<<<(N_OUT * BATCH) / 256, 256, 0, stream>>>(
        xeB, xT, w1_val, b1, gamma, beta, w3_val, b3,
        if_cnt, if_bkt, edge_src, out);
}

// Round 9
// 172.979 us; speedup vs baseline: 3.8656x; 1.0757x over previous
//
#include <hip/hip_runtime.h>

#define N_FUNC 10000
#define N_IN   2000
#define N_OUT  2000
#define CCH    8
#define K_FF   16
#define E_TOTAL 170000
#define E_FF    160000   // ff edges: dst[e] = e/16 (structural), src random func
#define E_W1    168000   // ff+if edges (dst < N_FUNC)
#define E_IF    8000
#define BATCH   64
#define N_LAYERS 4
#define EPS_LN  1e-5f
#define IF_CAP  16        // max if-in-degree of a func node (mean 0.8)
#define HROW    (BATCH * CCH)   // Hsum row: 512 ushorts (bf16) = 1 KB per node

// ---- bf16 pack helpers (fp32 math everywhere; RNE on store) ----
__device__ __forceinline__ float bfu_lo(unsigned int u) {   // even channel
    return __builtin_bit_cast(float, u << 16);
}
__device__ __forceinline__ float bfu_hi(unsigned int u) {   // odd channel
    return __builtin_bit_cast(float, u & 0xffff0000u);
}
__device__ __forceinline__ unsigned int bfpack2(float f0, float f1) {
    unsigned int x0 = __builtin_bit_cast(unsigned int, f0);
    unsigned int x1 = __builtin_bit_cast(unsigned int, f1);
    unsigned int r0 = (x0 + 0x7fffu + ((x0 >> 16) & 1u)) >> 16;
    unsigned int r1 = (x1 + 0x7fffu + ((x1 >> 16) & 1u)) & 0xffff0000u;
    return r0 | r1;
}

// fast GELU (validated R7: absmax unchanged vs exact erf)
__device__ __forceinline__ float fast_gelu(float x) {
    float x2 = x * x;
    float u  = x * __builtin_fmaf(0.044715f, x2, 1.0f);
    float e  = exp2f(-2.3022080f * u);     // sigmoid(1.5957691*u)
    return x * (1.0f / (1.0f + e));
}

// ---------------- prep 0: zero if-edge bucket counts ----------------

__global__ void zero_cnt(int* __restrict__ if_cnt) {
    int i = blockIdx.x * blockDim.x + threadIdx.x;
    if (i < N_FUNC) if_cnt[i] = 0;
}

// ---------------- prep 1: if-edge buckets + x transpose ----------------

__global__ void fill_prep(const int* __restrict__ dst, const float* __restrict__ x,
                          int* __restrict__ if_cnt, int* __restrict__ if_bkt,
                          float* __restrict__ xT) {
    int i = blockIdx.x * blockDim.x + threadIdx.x;
    if (i < E_IF) {
        int e = E_FF + i;
        int d = dst[e];
        int pos = atomicAdd(&if_cnt[d], 1);
        if_bkt[d * IF_CAP + pos] = e;
    }
    if (i < N_IN * BATCH) {
        int col = i >> 6, lane = i & 63;
        xT[col * BATCH + lane] = x[lane * N_IN + col];
    }
}

// ---------------- shared pieces ----------------

// if-edge contributions: virtual xe value = xT[i] + lf*b3[e]
__device__ __forceinline__ void if_accum(
        float* __restrict__ acc, const float* __restrict__ xT,
        const float* __restrict__ w1, const float* __restrict__ b3,
        const int* __restrict__ if_cnt, const int* __restrict__ if_bkt,
        int f, int lane, float lf) {
    int icnt = if_cnt[f];
    for (int j = 0; j < icnt; j++) {
        int e = if_bkt[f * IF_CAP + j];
        int ii = (e - E_FF) >> 2;
        float xv = xT[ii * BATCH + lane] + lf * b3[e];
        const float* wr = w1 + (size_t)e * CCH;
        #pragma unroll
        for (int c = 0; c < CCH; c++) acc[c] += xv * wr[c];
    }
}

__device__ __forceinline__ void ln_gelu(
        const float* __restrict__ acc, const float* __restrict__ gamma,
        const float* __restrict__ beta, int f, float* __restrict__ hreg) {
    float mu = 0.f;
    #pragma unroll
    for (int c = 0; c < CCH; c++) mu += acc[c];
    mu *= 0.125f;
    float var = 0.f;
    #pragma unroll
    for (int c = 0; c < CCH; c++) { float d = acc[c] - mu; var += d * d; }
    var *= 0.125f;
    float rs = rsqrtf(var + EPS_LN);
    #pragma unroll
    for (int c = 0; c < CCH; c++) {
        float g = (acc[c] - mu) * rs * gamma[f * CCH + c] + beta[f * CCH + c];
        hreg[c] = fast_gelu(g);
    }
}

// full gather-form h for node f with coefficient lf = (block_idx-1):
// ff in-edge value = lf*b3[e] + dot8(w3[e], Hsum_old[src[e]])
__device__ __forceinline__ void compute_h_gather(
        const unsigned short* __restrict__ Hold, const float* __restrict__ xT,
        const float* __restrict__ w1, const float* __restrict__ b1,
        const float* __restrict__ gamma, const float* __restrict__ beta,
        const float* __restrict__ w3, const float* __restrict__ b3,
        const int* __restrict__ esrc, const int* __restrict__ if_cnt,
        const int* __restrict__ if_bkt, int f, int lane, float lf,
        float* __restrict__ hreg) {
    // in-edge src ids: contiguous, wave-uniform -> s_loads
    int srcs[K_FF];
    #pragma unroll
    for (int k = 0; k < K_FF; k++) srcs[k] = esrc[f * K_FF + k];
    // 16 coalesced 1 KB gathers of Hsum rows (bf16, 16 B/lane), all in flight
    uint4 hrow[K_FF];
    #pragma unroll
    for (int k = 0; k < K_FF; k++)
        hrow[k] = *(const uint4*)(Hold + (size_t)srcs[k] * HROW + lane * CCH);

    float acc[CCH];
    #pragma unroll
    for (int c = 0; c < CCH; c++) acc[c] = b1[f * CCH + c];

    #pragma unroll
    for (int k = 0; k < K_FF; k++) {
        int e = f * K_FF + k;
        const float* w3r = w3 + (size_t)e * CCH;   // in-edge rows: contiguous
        const float* w1r = w1 + (size_t)e * CCH;
        float hv[CCH];
        hv[0] = bfu_lo(hrow[k].x); hv[1] = bfu_hi(hrow[k].x);
        hv[2] = bfu_lo(hrow[k].y); hv[3] = bfu_hi(hrow[k].y);
        hv[4] = bfu_lo(hrow[k].z); hv[5] = bfu_hi(hrow[k].z);
        hv[6] = bfu_lo(hrow[k].w); hv[7] = bfu_hi(hrow[k].w);
        float xv = lf * b3[e];
        #pragma unroll
        for (int c = 0; c < CCH; c++) xv += hv[c] * w3r[c];
        #pragma unroll
        for (int c = 0; c < CCH; c++) acc[c] += xv * w1r[c];
    }
    if_accum(acc, xT, w1, b3, if_cnt, if_bkt, f, lane, lf);
    ln_gelu(acc, gamma, beta, f, hreg);
}

// ---------------- block 1: xe_0 = 0 on ff edges; Hsum_1 = h_1 ----------------

__global__ __launch_bounds__(256, 4) void block_first(
        unsigned short* __restrict__ Hnew, const float* __restrict__ xT,
        const float* __restrict__ w1, const float* __restrict__ b1,
        const float* __restrict__ gamma, const float* __restrict__ beta,
        const float* __restrict__ b3, const int* __restrict__ if_cnt,
        const int* __restrict__ if_bkt) {
    int wid = (blockIdx.x * blockDim.x + threadIdx.x) >> 6;
    int lane = threadIdx.x & 63;
    int f = __builtin_amdgcn_readfirstlane(wid);
    if (f >= N_FUNC) return;
    float acc[CCH];
    #pragma unroll
    for (int c = 0; c < CCH; c++) acc[c] = b1[f * CCH + c];
    if_accum(acc, xT, w1, b3, if_cnt, if_bkt, f, lane, 0.0f);
    float h[CCH];
    ln_gelu(acc, gamma, beta, f, h);
    uint4 o;
    o.x = bfpack2(h[0], h[1]); o.y = bfpack2(h[2], h[3]);
    o.z = bfpack2(h[4], h[5]); o.w = bfpack2(h[6], h[7]);
    *(uint4*)(Hnew + (size_t)f * HROW + lane * CCH) = o;
}

// ---------------- blocks 2,3: gather + Hsum RMW ----------------

__global__ __launch_bounds__(256, 4) void block_mid(
        const unsigned short* __restrict__ Hold, unsigned short* __restrict__ Hnew,
        const float* __restrict__ xT, const float* __restrict__ w1,
        const float* __restrict__ b1, const float* __restrict__ gamma,
        const float* __restrict__ beta, const float* __restrict__ w3,
        const float* __restrict__ b3, const int* __restrict__ esrc,
        const int* __restrict__ if_cnt, const int* __restrict__ if_bkt, float lf) {
    int wid = (blockIdx.x * blockDim.x + threadIdx.x) >> 6;
    int lane = threadIdx.x & 63;
    int f = __builtin_amdgcn_readfirstlane(wid);
    if (f >= N_FUNC) return;
    float h[CCH];
    compute_h_gather(Hold, xT, w1, b1, gamma, beta, w3, b3, esrc,
                     if_cnt, if_bkt, f, lane, lf, h);
    // Hsum_new[f] = Hsum_old[f] + h  (own row, coalesced)
    uint4 own = *(const uint4*)(Hold + (size_t)f * HROW + lane * CCH);
    uint4 o;
    o.x = bfpack2(bfu_lo(own.x) + h[0], bfu_hi(own.x) + h[1]);
    o.y = bfpack2(bfu_lo(own.y) + h[2], bfu_hi(own.y) + h[3]);
    o.z = bfpack2(bfu_lo(own.z) + h[4], bfu_hi(own.z) + h[5]);
    o.w = bfpack2(bfu_lo(own.w) + h[6], bfu_hi(own.w) + h[7]);
    *(uint4*)(Hnew + (size_t)f * HROW + lane * CCH) = o;
}

// ---------------- block 4 + output: only the 2000 fo edges ----------------
// out = xe_4[e]/4 = b3[e] + 0.25 * w3[p] . (Hsum_3[s] + h_4[s])

__global__ __launch_bounds__(256, 4) void block_out(
        const unsigned short* __restrict__ Hold, const float* __restrict__ xT,
        const float* __restrict__ w1, const float* __restrict__ b1,
        const float* __restrict__ gamma, const float* __restrict__ beta,
        const float* __restrict__ w3, const float* __restrict__ b3,
        const int* __restrict__ esrc, const int* __restrict__ if_cnt,
        const int* __restrict__ if_bkt, float* __restrict__ out) {
    int wid = (blockIdx.x * blockDim.x + threadIdx.x) >> 6;   // fo index
    int lane = threadIdx.x & 63;
    int j = __builtin_amdgcn_readfirstlane(wid);
    if (j >= N_OUT) return;
    int e = E_W1 + j;
    int s = __builtin_amdgcn_readfirstlane(esrc[e]);

    float h[CCH];
    compute_h_gather(Hold, xT, w1, b1, gamma, beta, w3, b3, esrc,
                     if_cnt, if_bkt, s, lane, 3.0f, h);
    uint4 own = *(const uint4*)(Hold + (size_t)s * HROW + lane * CCH);
    float Hfin[CCH];
    Hfin[0] = bfu_lo(own.x) + h[0]; Hfin[1] = bfu_hi(own.x) + h[1];
    Hfin[2] = bfu_lo(own.y) + h[2]; Hfin[3] = bfu_hi(own.y) + h[3];
    Hfin[4] = bfu_lo(own.z) + h[4]; Hfin[5] = bfu_hi(own.z) + h[5];
    Hfin[6] = bfu_lo(own.w) + h[6]; Hfin[7] = bfu_hi(own.w) + h[7];

    int p = e - E_IF;
    const float* w3r = w3 + (size_t)p * CCH;
    float acc = 0.f;
    #pragma unroll
    for (int c = 0; c < CCH; c++) acc += Hfin[c] * w3r[c];
    out[lane * N_OUT + j] = b3[e] + 0.25f * acc;
}

// ---------------- launch ----------------

extern "C" void kernel_launch(void* const* d_in, const int* in_sizes, int n_in,
                              void* d_out, int out_size, void* d_ws, size_t ws_size,
                              hipStream_t stream) {
    const float* x      = (const float*)d_in[0];
    const float* w1_val = (const float*)d_in[1];
    const float* b1     = (const float*)d_in[2];
    const float* w3_val = (const float*)d_in[3];
    const float* b3     = (const float*)d_in[4];
    const float* gamma  = (const float*)d_in[5];
    const float* beta   = (const float*)d_in[6];
    const int* edge_src = (const int*)d_in[7];
    const int* edge_dst = (const int*)d_in[8];
    float* out = (float*)d_out;

    char* base = (char*)d_ws;
    size_t off = 0;
    auto alloc = [&](size_t bytes) -> void* {
        void* p = base + off;
        off += (bytes + 255) & ~(size_t)255;
        return p;
    };
    unsigned short* HsumA = (unsigned short*)alloc((size_t)N_FUNC * HROW * 2);  // 10.24 MB bf16
    unsigned short* HsumB = (unsigned short*)alloc((size_t)N_FUNC * HROW * 2);
    float* xT    = (float*)alloc((size_t)N_IN * BATCH * 4);
    int* if_cnt  = (int*)alloc(N_FUNC * 4);
    int* if_bkt  = (int*)alloc((size_t)N_FUNC * IF_CAP * 4);
    (void)ws_size; (void)in_sizes; (void)n_in; (void)out_size;

    zero_cnt<<<(N_FUNC + 255) / 256, 256, 0, stream>>>(if_cnt);
    fill_prep<<<(N_IN * BATCH + 255) / 256, 256, 0, stream>>>(
        edge_dst, x, if_cnt, if_bkt, xT);

    // block 1: Hsum_1 = h_1 -> A
    block_first<<<(N_FUNC * BATCH) / 256, 256, 0, stream>>>(
        HsumA, xT, w1_val, b1, gamma, beta, b3, if_cnt, if_bkt);
    // block 2: A -> B  (lf = 1)
    block_mid<<<(N_FUNC * BATCH) / 256, 256, 0, stream>>>(
        HsumA, HsumB, xT, w1_val, b1, gamma, beta, w3_val, b3,
        edge_src, if_cnt, if_bkt, 1.0f);
    // block 3: B -> A  (lf = 2)
    block_mid<<<(N_FUNC * BATCH) / 256, 256, 0, stream>>>(
        HsumB, HsumA, xT, w1_val, b1, gamma, beta, w3_val, b3,
        edge_src, if_cnt, if_bkt, 2.0f);
    // block 4 + output: reads Hsum_3 = A  (lf = 3)
    block_out<<<(N_OUT * BATCH) / 256, 256, 0, stream>>>(
        HsumA, xT, w1_val, b1, gamma, beta, w3_val, b3,
        edge_src, if_cnt, if_bkt, out);
}

// Round 10
// 169.770 us; speedup vs baseline: 3.9387x; 1.0189x over previous
//
#include <hip/hip_runtime.h>

#define N_FUNC 10000
#define N_IN   2000
#define N_OUT  2000
#define CCH    8
#define K_FF   16
#define E_TOTAL 170000
#define E_FF    160000   // ff edges: dst[e] = e/16 (structural), src random func
#define E_W1    168000   // ff+if edges (dst < N_FUNC)
#define E_IF    8000
#define BATCH   64
#define N_LAYERS 4
#define EPS_LN  1e-5f
#define IF_CAP  16        // max if-in-degree of a func node (mean 0.8)
#define HROW    (BATCH * CCH)   // Hsum row: 512 ushorts (bf16) = 1 KB per node

typedef float f2 __attribute__((ext_vector_type(2)));   // -> v_pk_fma_f32

// ---- bf16 helpers (fp32 math everywhere; RNE on store) ----
__device__ __forceinline__ f2 bfpair(unsigned int u) {   // packed pair -> 2 floats
    f2 r;
    r.x = __builtin_bit_cast(float, u << 16);
    r.y = __builtin_bit_cast(float, u & 0xffff0000u);
    return r;
}
__device__ __forceinline__ unsigned int bfpack2(float f0, float f1) {
    unsigned int x0 = __builtin_bit_cast(unsigned int, f0);
    unsigned int x1 = __builtin_bit_cast(unsigned int, f1);
    unsigned int r0 = (x0 + 0x7fffu + ((x0 >> 16) & 1u)) >> 16;
    unsigned int r1 = (x1 + 0x7fffu + ((x1 >> 16) & 1u)) & 0xffff0000u;
    return r0 | r1;
}

// fast GELU (validated R7: absmax unchanged vs exact erf)
__device__ __forceinline__ float fast_gelu(float x) {
    float x2 = x * x;
    float u  = x * __builtin_fmaf(0.044715f, x2, 1.0f);
    float e  = exp2f(-2.3022080f * u);     // sigmoid(1.5957691*u)
    return x * (1.0f / (1.0f + e));
}

// ---------------- prep: if-edge buckets + x transpose ----------------
// (if_cnt zeroed by hipMemsetAsync on the stream)

__global__ void fill_prep(const int* __restrict__ dst, const float* __restrict__ x,
                          int* __restrict__ if_cnt, int* __restrict__ if_bkt,
                          float* __restrict__ xT) {
    int i = blockIdx.x * blockDim.x + threadIdx.x;
    if (i < E_IF) {
        int e = E_FF + i;
        int d = dst[e];
        int pos = atomicAdd(&if_cnt[d], 1);
        if_bkt[d * IF_CAP + pos] = e;
    }
    if (i < N_IN * BATCH) {
        int col = i >> 6, lane = i & 63;
        xT[col * BATCH + lane] = x[lane * N_IN + col];
    }
}

// ---------------- shared pieces (float2-packed) ----------------

// if-edge contributions: virtual xe value = xT[i] + lf*b3[e]
__device__ __forceinline__ void if_accum(
        f2* __restrict__ acc2, const float* __restrict__ xT,
        const float* __restrict__ w1, const float* __restrict__ b3,
        const int* __restrict__ if_cnt, const int* __restrict__ if_bkt,
        int f, int lane, float lf) {
    int icnt = if_cnt[f];
    for (int j = 0; j < icnt; j++) {
        int e = if_bkt[f * IF_CAP + j];
        int ii = (e - E_FF) >> 2;
        float xv = xT[ii * BATCH + lane] + lf * b3[e];
        f2 xv2; xv2.x = xv; xv2.y = xv;
        const f2* w1v = (const f2*)(w1 + (size_t)e * CCH);
        #pragma unroll
        for (int q = 0; q < 4; q++) acc2[q] += xv2 * w1v[q];
    }
}

__device__ __forceinline__ void ln_gelu(
        const f2* __restrict__ acc2, const float* __restrict__ gamma,
        const float* __restrict__ beta, int f, f2* __restrict__ h2) {
    float mu = 0.f;
    #pragma unroll
    for (int q = 0; q < 4; q++) mu += acc2[q].x + acc2[q].y;
    mu *= 0.125f;
    float var = 0.f;
    #pragma unroll
    for (int q = 0; q < 4; q++) {
        float dx = acc2[q].x - mu, dy = acc2[q].y - mu;
        var += dx * dx + dy * dy;
    }
    var *= 0.125f;
    float rs = rsqrtf(var + EPS_LN);
    const f2* gv = (const f2*)(gamma + (size_t)f * CCH);
    const f2* bv = (const f2*)(beta + (size_t)f * CCH);
    f2 mu2; mu2.x = mu; mu2.y = mu;
    f2 rs2; rs2.x = rs; rs2.y = rs;
    #pragma unroll
    for (int q = 0; q < 4; q++) {
        f2 g = (acc2[q] - mu2) * rs2 * gv[q] + bv[q];
        h2[q].x = fast_gelu(g.x);
        h2[q].y = fast_gelu(g.y);
    }
}

// gather-form h for node f, coefficient lf = (block_idx-1):
// ff in-edge value = lf*b3[e] + dot8(w3[e], Hsum_old[src[e]])
__device__ __forceinline__ void compute_h_gather(
        const unsigned short* __restrict__ Hold, const float* __restrict__ xT,
        const float* __restrict__ w1, const float* __restrict__ b1,
        const float* __restrict__ gamma, const float* __restrict__ beta,
        const float* __restrict__ w3, const float* __restrict__ b3,
        const int* __restrict__ esrc, const int* __restrict__ if_cnt,
        const int* __restrict__ if_bkt, int f, int lane, float lf,
        f2* __restrict__ h2) {
    // in-edge src ids: contiguous, wave-uniform -> s_loads
    int srcs[K_FF];
    #pragma unroll
    for (int k = 0; k < K_FF; k++) srcs[k] = esrc[f * K_FF + k];
    // 16 coalesced 1 KB gathers of Hsum rows (bf16, 16 B/lane), all in flight
    uint4 hrow[K_FF];
    #pragma unroll
    for (int k = 0; k < K_FF; k++)
        hrow[k] = *(const uint4*)(Hold + (size_t)srcs[k] * HROW + lane * CCH);

    const f2* b1v = (const f2*)(b1 + (size_t)f * CCH);
    f2 acc2[4];
    #pragma unroll
    for (int q = 0; q < 4; q++) acc2[q] = b1v[q];

    #pragma unroll
    for (int k = 0; k < K_FF; k++) {
        int e = f * K_FF + k;
        const f2* w3v = (const f2*)(w3 + (size_t)e * CCH);   // contiguous rows
        const f2* w1v = (const f2*)(w1 + (size_t)e * CCH);
        f2 d = bfpair(hrow[k].x) * w3v[0];
        d += bfpair(hrow[k].y) * w3v[1];
        d += bfpair(hrow[k].z) * w3v[2];
        d += bfpair(hrow[k].w) * w3v[3];
        float xv = d.x + d.y + lf * b3[e];
        f2 xv2; xv2.x = xv; xv2.y = xv;
        #pragma unroll
        for (int q = 0; q < 4; q++) acc2[q] += xv2 * w1v[q];
    }
    if_accum(acc2, xT, w1, b3, if_cnt, if_bkt, f, lane, lf);
    ln_gelu(acc2, gamma, beta, f, h2);
}

// ---------------- block 1: xe_0 = 0 on ff edges; Hsum_1 = h_1 ----------------

__global__ __launch_bounds__(256, 4) void block_first(
        unsigned short* __restrict__ Hnew, const float* __restrict__ xT,
        const float* __restrict__ w1, const float* __restrict__ b1,
        const float* __restrict__ gamma, const float* __restrict__ beta,
        const float* __restrict__ b3, const int* __restrict__ if_cnt,
        const int* __restrict__ if_bkt) {
    int wid = (blockIdx.x * blockDim.x + threadIdx.x) >> 6;
    int lane = threadIdx.x & 63;
    int f = __builtin_amdgcn_readfirstlane(wid);
    if (f >= N_FUNC) return;
    const f2* b1v = (const f2*)(b1 + (size_t)f * CCH);
    f2 acc2[4];
    #pragma unroll
    for (int q = 0; q < 4; q++) acc2[q] = b1v[q];
    if_accum(acc2, xT, w1, b3, if_cnt, if_bkt, f, lane, 0.0f);
    f2 h2[4];
    ln_gelu(acc2, gamma, beta, f, h2);
    uint4 o;
    o.x = bfpack2(h2[0].x, h2[0].y); o.y = bfpack2(h2[1].x, h2[1].y);
    o.z = bfpack2(h2[2].x, h2[2].y); o.w = bfpack2(h2[3].x, h2[3].y);
    *(uint4*)(Hnew + (size_t)f * HROW + lane * CCH) = o;
}

// ---------------- blocks 2,3: gather + Hsum RMW ----------------

__global__ __launch_bounds__(256, 4) void block_mid(
        const unsigned short* __restrict__ Hold, unsigned short* __restrict__ Hnew,
        const float* __restrict__ xT, const float* __restrict__ w1,
        const float* __restrict__ b1, const float* __restrict__ gamma,
        const float* __restrict__ beta, const float* __restrict__ w3,
        const float* __restrict__ b3, const int* __restrict__ esrc,
        const int* __restrict__ if_cnt, const int* __restrict__ if_bkt, float lf) {
    int wid = (blockIdx.x * blockDim.x + threadIdx.x) >> 6;
    int lane = threadIdx.x & 63;
    int f = __builtin_amdgcn_readfirstlane(wid);
    if (f >= N_FUNC) return;
    // own row issued early to overlap with the gather round
    uint4 own = *(const uint4*)(Hold + (size_t)f * HROW + lane * CCH);
    f2 h2[4];
    compute_h_gather(Hold, xT, w1, b1, gamma, beta, w3, b3, esrc,
                     if_cnt, if_bkt, f, lane, lf, h2);
    // Hsum_new[f] = Hsum_old[f] + h  (own row, coalesced)
    f2 s0 = bfpair(own.x) + h2[0];
    f2 s1 = bfpair(own.y) + h2[1];
    f2 s2 = bfpair(own.z) + h2[2];
    f2 s3 = bfpair(own.w) + h2[3];
    uint4 o;
    o.x = bfpack2(s0.x, s0.y); o.y = bfpack2(s1.x, s1.y);
    o.z = bfpack2(s2.x, s2.y); o.w = bfpack2(s3.x, s3.y);
    *(uint4*)(Hnew + (size_t)f * HROW + lane * CCH) = o;
}

// ---------------- block 4 + output: only the 2000 fo edges ----------------
// out = xe_4[e]/4 = b3[e] + 0.25 * w3[p] . (Hsum_3[s] + h_4[s])

__global__ __launch_bounds__(256, 4) void block_out(
        const unsigned short* __restrict__ Hold, const float* __restrict__ xT,
        const float* __restrict__ w1, const float* __restrict__ b1,
        const float* __restrict__ gamma, const float* __restrict__ beta,
        const float* __restrict__ w3, const float* __restrict__ b3,
        const int* __restrict__ esrc, const int* __restrict__ if_cnt,
        const int* __restrict__ if_bkt, float* __restrict__ out) {
    int wid = (blockIdx.x * blockDim.x + threadIdx.x) >> 6;   // fo index
    int lane = threadIdx.x & 63;
    int j = __builtin_amdgcn_readfirstlane(wid);
    if (j >= N_OUT) return;
    int e = E_W1 + j;
    int s = __builtin_amdgcn_readfirstlane(esrc[e]);

    uint4 own = *(const uint4*)(Hold + (size_t)s * HROW + lane * CCH);
    f2 h2[4];
    compute_h_gather(Hold, xT, w1, b1, gamma, beta, w3, b3, esrc,
                     if_cnt, if_bkt, s, lane, 3.0f, h2);
    f2 Hf0 = bfpair(own.x) + h2[0];
    f2 Hf1 = bfpair(own.y) + h2[1];
    f2 Hf2 = bfpair(own.z) + h2[2];
    f2 Hf3 = bfpair(own.w) + h2[3];

    int p = e - E_IF;
    const f2* w3v = (const f2*)(w3 + (size_t)p * CCH);
    f2 a = Hf0 * w3v[0];
    a += Hf1 * w3v[1];
    a += Hf2 * w3v[2];
    a += Hf3 * w3v[3];
    out[lane * N_OUT + j] = b3[e] + 0.25f * (a.x + a.y);
}

// ---------------- launch ----------------

extern "C" void kernel_launch(void* const* d_in, const int* in_sizes, int n_in,
                              void* d_out, int out_size, void* d_ws, size_t ws_size,
                              hipStream_t stream) {
    const float* x      = (const float*)d_in[0];
    const float* w1_val = (const float*)d_in[1];
    const float* b1     = (const float*)d_in[2];
    const float* w3_val = (const float*)d_in[3];
    const float* b3     = (const float*)d_in[4];
    const float* gamma  = (const float*)d_in[5];
    const float* beta   = (const float*)d_in[6];
    const int* edge_src = (const int*)d_in[7];
    const int* edge_dst = (const int*)d_in[8];
    float* out = (float*)d_out;

    char* base = (char*)d_ws;
    size_t off = 0;
    auto alloc = [&](size_t bytes) -> void* {
        void* p = base + off;
        off += (bytes + 255) & ~(size_t)255;
        return p;
    };
    unsigned short* HsumA = (unsigned short*)alloc((size_t)N_FUNC * HROW * 2);  // 10.24 MB bf16
    unsigned short* HsumB = (unsigned short*)alloc((size_t)N_FUNC * HROW * 2);
    float* xT    = (float*)alloc((size_t)N_IN * BATCH * 4);
    int* if_cnt  = (int*)alloc(N_FUNC * 4);
    int* if_bkt  = (int*)alloc((size_t)N_FUNC * IF_CAP * 4);
    (void)ws_size; (void)in_sizes; (void)n_in; (void)out_size;

    hipMemsetAsync(if_cnt, 0, N_FUNC * 4, stream);   // capture-legal (harness uses it too)
    fill_prep<<<(N_IN * BATCH + 255) / 256, 256, 0, stream>>>(
        edge_dst, x, if_cnt, if_bkt, xT);

    // block 1: Hsum_1 = h_1 -> A
    block_first<<<(N_FUNC * BATCH) / 256, 256, 0, stream>>>(
        HsumA, xT, w1_val, b1, gamma, beta, b3, if_cnt, if_bkt);
    // block 2: A -> B  (lf = 1)
    block_mid<<<(N_FUNC * BATCH) / 256, 256, 0, stream>>>(
        HsumA, HsumB, xT, w1_val, b1, gamma, beta, w3_val, b3,
        edge_src, if_cnt, if_bkt, 1.0f);
    // block 3: B -> A  (lf = 2)
    block_mid<<<(N_FUNC * BATCH) / 256, 256, 0, stream>>>(
        HsumB, HsumA, xT, w1_val, b1, gamma, beta, w3_val, b3,
        edge_src, if_cnt, if_bkt, 2.0f);
    // block 4 + output: reads Hsum_3 = A  (lf = 3)
    block_out<<<(N_OUT * BATCH) / 256, 256, 0, stream>>>(
        HsumA, xT, w1_val, b1, gamma, beta, w3_val, b3,
        edge_src, if_cnt, if_bkt, out);
}